// Round 5
// baseline (203.602 us; speedup 1.0000x reference)
//
#include <hip/hip_runtime.h>

// Involution (B=8, H=W=192, C=64, G=4, K=3, R=4) — round 5: two-kernel split.
// R2/R4 post-mortem: fused structure caps at 18 waves/CU (1 thread/px in
// Phase A) and the compiler won't hold a 9-deep load pipeline (VGPR stuck
// at 64) -> latency-bound at 96 us. Split buys TLP with HBM traffic:
//   K1 kern-gen: 1 thr/px, writes kern[px][36] fp32 to d_ws (42.5 MB).
//   K2 involution: 1 thr per (px,chunk) = 73728 waves = 288 waves/CU of
//      work; 18 independent coalesced 16B loads/thread; branchless edges.
// Floors: K1 ~19 us, K2 ~31 us @ 6.3 TB/s.

#define B_   8
#define H_   192
#define W_   192
#define CR_  16
#define NPX  (B_*H_*W_)                 // 294912 pixels
#define KWS  ((size_t)NPX * 36 * 4)     // 42.5 MB kern workspace

constexpr float BN_EPS = 1e-3f;

// ------------------------------ K1: kern-gen --------------------------------
// 256 thr/block, 1 thread = 1 pixel. 1152 blocks; img = bid&7 (XCD k = img k).
__global__ __launch_bounds__(256)
void kern_gen(const float* __restrict__ x,
              const float* __restrict__ w1,
              const float* __restrict__ b1,
              const float* __restrict__ gamma,
              const float* __restrict__ beta,
              const float* __restrict__ mean,
              const float* __restrict__ var,
              const float* __restrict__ w2,
              const float* __restrict__ b2,
              float* __restrict__ kern)
{
    const int bid = blockIdx.x;                  // 1152 = 8 * 144
    const int img = bid & 7;
    const int px_in_img = (bid >> 3) * 256 + threadIdx.x;   // 0..36863
    const int px = img * (H_ * W_) + px_in_img;

    const float4* xp = reinterpret_cast<const float4*>(x + ((size_t)px << 6));

    float td[CR_];
    #pragma unroll
    for (int d = 0; d < CR_; ++d) td[d] = 0.f;

    // t = x @ w1  (weight addresses wave-uniform -> s_load on SMEM pipe)
    #pragma unroll
    for (int c4 = 0; c4 < 16; ++c4) {
        const float4 xv = xp[c4];
        const float xs[4] = {xv.x, xv.y, xv.z, xv.w};
        #pragma unroll
        for (int k = 0; k < 4; ++k) {
            const float* wr = w1 + (c4 * 4 + k) * CR_;
            #pragma unroll
            for (int d = 0; d < CR_; ++d)
                td[d] = fmaf(xs[k], wr[d], td[d]);
        }
    }

    // + b1, BN (inference), ReLU — folded affine
    #pragma unroll
    for (int d = 0; d < CR_; ++d) {
        const float a = gamma[d] * rsqrtf(var[d] + BN_EPS);
        const float c = (b1[d] - mean[d]) * a + beta[d];
        td[d] = fmaxf(fmaf(td[d], a, c), 0.f);
    }

    // kern = t @ w2 + b2   (e = tap*4 + g, so float4 t = ke[4t..4t+3])
    float ke[36];
    #pragma unroll
    for (int e = 0; e < 36; ++e) ke[e] = b2[e];
    #pragma unroll
    for (int d = 0; d < CR_; ++d) {
        const float t = td[d];
        const float* wr = w2 + d * 36;
        #pragma unroll
        for (int e = 0; e < 36; ++e)
            ke[e] = fmaf(t, wr[e], ke[e]);
    }

    float4* kq = reinterpret_cast<float4*>(kern + (size_t)px * 36);
    #pragma unroll
    for (int t = 0; t < 9; ++t)
        kq[t] = make_float4(ke[4 * t], ke[4 * t + 1], ke[4 * t + 2], ke[4 * t + 3]);
}

// ------------------------------ K2: involution ------------------------------
// 1 thread per (pixel, float4 channel-chunk): task = px*16 + c4i.
// Wave = 4 consecutive pixels x 16 chunks = 4 KB contiguous loads/stores.
// 18432 blocks; swizzle gives XCD k exactly image k for L2 halo locality.
__global__ __launch_bounds__(256)
void invol_apply(const float* __restrict__ x,
                 const float* __restrict__ kern,
                 float* __restrict__ out)
{
    const int bid = blockIdx.x;                  // 18432 = 8 * 2304
    const int bsw = (bid & 7) * 2304 + (bid >> 3);
    const int task = bsw * 256 + threadIdx.x;
    const int px  = task >> 4;
    const int c4i = task & 15;

    const int img = px / (H_ * W_);
    const int rem = px - img * (H_ * W_);
    const int h = rem / W_;
    const int w = rem - h * W_;

    const float* ximg = x + (((size_t)(img * H_ * W_)) << 6);

    // 9 clamped tap loads + 9 kern loads, all independent -> batched issue.
    float4 xv[9];
    int m9 = 0;
    #pragma unroll
    for (int ti = 0; ti < 3; ++ti) {
        int hh = h + ti - 1;
        const bool vh = (unsigned)hh < (unsigned)H_;
        hh = hh < 0 ? 0 : (hh >= H_ ? H_ - 1 : hh);
        #pragma unroll
        for (int tj = 0; tj < 3; ++tj) {
            int ww = w + tj - 1;
            const bool v = vh && ((unsigned)ww < (unsigned)W_);
            ww = ww < 0 ? 0 : (ww >= W_ ? W_ - 1 : ww);
            if (v) m9 |= 1 << (ti * 3 + tj);
            xv[ti * 3 + tj] = reinterpret_cast<const float4*>(
                ximg + (((size_t)(hh * W_ + ww)) << 6))[c4i];
        }
    }

    const float4* kq = reinterpret_cast<const float4*>(kern + (size_t)px * 36);
    float4 acc = make_float4(0.f, 0.f, 0.f, 0.f);
    #pragma unroll
    for (int t = 0; t < 9; ++t) {
        const bool v = (m9 >> t) & 1;
        const float4 kv = kq[t];
        const float kx = v ? kv.x : 0.f;
        const float ky = v ? kv.y : 0.f;
        const float kz = v ? kv.z : 0.f;
        const float kw = v ? kv.w : 0.f;
        acc.x = fmaf(kx, xv[t].x, acc.x);
        acc.y = fmaf(ky, xv[t].y, acc.y);
        acc.z = fmaf(kz, xv[t].z, acc.z);
        acc.w = fmaf(kw, xv[t].w, acc.w);
    }
    reinterpret_cast<float4*>(out)[task] = acc;
}

// --------------------- Fallback: R2 fused kernel (ws too small) -------------
#define TH_  8
#define TW_  16
#define TILES_X (W_/TW_)
#define NPIX (TH_*TW_)

template <bool INTERIOR>
__device__ __forceinline__ void phase_b_f(const float* __restrict__ x,
                                          float* __restrict__ out,
                                          const float4* __restrict__ s_kern,
                                          int img, int th0, int tw0, int tid)
{
    const int prow = tid >> 4;
    const int c4i  = tid & 15;
    const float* ximg = x + (((size_t)(img * H_ * W_)) << 6);
    float* oimg = out + (((size_t)(img * H_ * W_)) << 6);

    for (int i = 0; i < 16; ++i) {
        const int q = i * 8 + prow;
        const int h = th0 + (q >> 4), w = tw0 + (q & 15);
        const float4* kq = &s_kern[q * 9];
        float4 acc = make_float4(0.f, 0.f, 0.f, 0.f);
        #pragma unroll
        for (int ti = 0; ti < 3; ++ti) {
            int hh = h + ti - 1;
            bool vh = true;
            if (!INTERIOR) { vh = (unsigned)hh < (unsigned)H_; hh = hh < 0 ? 0 : (hh >= H_ ? H_-1 : hh); }
            #pragma unroll
            for (int tj = 0; tj < 3; ++tj) {
                int ww = w + tj - 1;
                bool v = vh;
                if (!INTERIOR) { v = vh && ((unsigned)ww < (unsigned)W_); ww = ww < 0 ? 0 : (ww >= W_-1 ? W_-1 : ww); }
                const float4 xvv = reinterpret_cast<const float4*>(
                    ximg + (((size_t)(hh * W_ + ww)) << 6))[c4i];
                float4 kv = kq[ti * 3 + tj];
                if (!INTERIOR) { kv.x = v?kv.x:0.f; kv.y = v?kv.y:0.f; kv.z = v?kv.z:0.f; kv.w = v?kv.w:0.f; }
                acc.x = fmaf(kv.x, xvv.x, acc.x);
                acc.y = fmaf(kv.y, xvv.y, acc.y);
                acc.z = fmaf(kv.z, xvv.z, acc.z);
                acc.w = fmaf(kv.w, xvv.w, acc.w);
            }
        }
        reinterpret_cast<float4*>(oimg + (((size_t)(h * W_ + w)) << 6))[c4i] = acc;
    }
}

__global__ __launch_bounds__(128, 4)
void invol_fused(const float* __restrict__ x, const float* __restrict__ w1,
                 const float* __restrict__ b1, const float* __restrict__ gamma,
                 const float* __restrict__ beta, const float* __restrict__ mean,
                 const float* __restrict__ var, const float* __restrict__ w2,
                 const float* __restrict__ b2, float* __restrict__ out)
{
    __shared__ float4 s_kern[NPIX * 9];
    const int bid = blockIdx.x;
    const int img = bid & 7;
    const int tin = bid >> 3;
    const int th0 = (tin / TILES_X) * TH_;
    const int tw0 = (tin % TILES_X) * TW_;
    const int tid = threadIdx.x;
    {
        const int h = th0 + (tid >> 4), w = tw0 + (tid & 15);
        const float4* xp = reinterpret_cast<const float4*>(
            x + (((size_t)((img * H_ + h) * W_ + w)) << 6));
        float td[CR_];
        #pragma unroll
        for (int d = 0; d < CR_; ++d) td[d] = 0.f;
        #pragma unroll
        for (int c4 = 0; c4 < 16; ++c4) {
            const float4 xv = xp[c4];
            const float xs[4] = {xv.x, xv.y, xv.z, xv.w};
            #pragma unroll
            for (int k = 0; k < 4; ++k) {
                const float* wr = w1 + (c4 * 4 + k) * CR_;
                #pragma unroll
                for (int d = 0; d < CR_; ++d) td[d] = fmaf(xs[k], wr[d], td[d]);
            }
        }
        #pragma unroll
        for (int d = 0; d < CR_; ++d) {
            const float a = gamma[d] * rsqrtf(var[d] + BN_EPS);
            const float c = (b1[d] - mean[d]) * a + beta[d];
            td[d] = fmaxf(fmaf(td[d], a, c), 0.f);
        }
        float ke[36];
        #pragma unroll
        for (int e = 0; e < 36; ++e) ke[e] = b2[e];
        #pragma unroll
        for (int d = 0; d < CR_; ++d) {
            const float t = td[d];
            const float* wr = w2 + d * 36;
            #pragma unroll
            for (int e = 0; e < 36; ++e) ke[e] = fmaf(t, wr[e], ke[e]);
        }
        float4* skq = &s_kern[tid * 9];
        #pragma unroll
        for (int t9 = 0; t9 < 9; ++t9)
            skq[t9] = make_float4(ke[4*t9], ke[4*t9+1], ke[4*t9+2], ke[4*t9+3]);
    }
    __syncthreads();
    const bool interior = (th0 > 0) && (th0 + TH_ < H_) &&
                          (tw0 > 0) && (tw0 + TW_ < W_);
    if (interior) phase_b_f<true>(x, out, s_kern, img, th0, tw0, tid);
    else          phase_b_f<false>(x, out, s_kern, img, th0, tw0, tid);
}

extern "C" void kernel_launch(void* const* d_in, const int* in_sizes, int n_in,
                              void* d_out, int out_size, void* d_ws, size_t ws_size,
                              hipStream_t stream) {
    const float* x     = (const float*)d_in[0];
    const float* w1    = (const float*)d_in[1];
    const float* b1    = (const float*)d_in[2];
    const float* gamma = (const float*)d_in[3];
    const float* beta  = (const float*)d_in[4];
    const float* mean  = (const float*)d_in[5];
    const float* var   = (const float*)d_in[6];
    const float* w2    = (const float*)d_in[7];
    const float* b2    = (const float*)d_in[8];
    float* out = (float*)d_out;

    if (ws_size >= KWS) {
        float* kern = (float*)d_ws;
        kern_gen<<<dim3(NPX / 256), dim3(256), 0, stream>>>(
            x, w1, b1, gamma, beta, mean, var, w2, b2, kern);
        invol_apply<<<dim3(NPX * 16 / 256), dim3(256), 0, stream>>>(
            x, kern, out);
    } else {
        invol_fused<<<dim3(NPX / NPIX), dim3(128), 0, stream>>>(
            x, w1, b1, gamma, beta, mean, var, w2, b2, out);
    }
}